// Round 1
// baseline (180.235 us; speedup 1.0000x reference)
//
#include <hip/hip_runtime.h>

#define FOCAL_GAMMA_IS_2 1
#define DIRECTIONAL_PENALTY 1.5f
#define CONFIDENCE_WEIGHT 0.1f

__global__ __launch_bounds__(256) void trading_loss_kernel(
    const float* __restrict__ logits,    // [B,3]
    const int*   __restrict__ targets,   // [B]
    const float* __restrict__ cw,        // [3]
    float*       __restrict__ out,       // [1], pre-zeroed
    int nquads,                          // B/4
    float inv_b)
{
    const float w0 = cw[0], w1 = cw[1], w2 = cw[2];

    const float4* __restrict__ lg4 = (const float4*)logits;
    const int4*   __restrict__ tg4 = (const int4*)targets;

    float acc = 0.0f;
    int tid    = blockIdx.x * blockDim.x + threadIdx.x;
    int stride = gridDim.x * blockDim.x;

    for (int q = tid; q < nquads; q += stride) {
        // 4 rows of 3 logits = 12 floats = 3 float4 (16B-aligned since 4 rows = 48B)
        float4 v0 = lg4[3 * q + 0];
        float4 v1 = lg4[3 * q + 1];
        float4 v2 = lg4[3 * q + 2];
        int4   tg = tg4[q];

        float ra[4] = {v0.x, v0.w, v1.z, v2.y};
        float rb[4] = {v0.y, v1.x, v1.w, v2.z};
        float rc[4] = {v0.z, v1.y, v2.x, v2.w};
        int   tt[4] = {tg.x, tg.y, tg.z, tg.w};

        #pragma unroll
        for (int r = 0; r < 4; ++r) {
            float a = ra[r], b = rb[r], c = rc[r];
            int t = tt[r];

            // argmax with first-max tie semantics (strict >)
            int pred = 0;
            float m = a;
            if (b > m) { m = b; pred = 1; }
            if (c > m) { m = c; pred = 2; }

            float e0 = __expf(a - m);
            float e1 = __expf(b - m);
            float e2 = __expf(c - m);
            float s = e0 + e1 + e2;
            float inv_s = 1.0f / s;

            // p_t = softmax prob of target; ce = -log_softmax[target]
            float et = (t == 0) ? e0 : ((t == 1) ? e1 : e2);
            float lt = (t == 0) ? a  : ((t == 1) ? b  : c);
            float p_t = et * inv_s;
            float ce = (m - lt) + __logf(s);

            float w  = (t == 0) ? w0 : ((t == 1) ? w1 : w2);
            float omp = 1.0f - p_t;
            float contrib = w * omp * omp * ce;   // focal

            // penalty matrix is Toeplitz in |pred - t|: 0 -> 0, 1 -> 0.5, 2 -> 1.5
            int d = pred - t; d = (d < 0) ? -d : d;
            float pen = (d == 1) ? 0.5f : ((d == 2) ? 1.5f : 0.0f);
            contrib += DIRECTIONAL_PENALTY * pen;

            // confidence: (1-correct) * max_prob; max_prob = exp(m-m)/s = 1/s
            if (pred != t) contrib += CONFIDENCE_WEIGHT * inv_s;

            acc += contrib;
        }
    }

    // wave64 shuffle reduction
    #pragma unroll
    for (int off = 32; off > 0; off >>= 1)
        acc += __shfl_down(acc, off, 64);

    __shared__ float sdata[4];
    int lane = threadIdx.x & 63;
    int wid  = threadIdx.x >> 6;
    if (lane == 0) sdata[wid] = acc;
    __syncthreads();
    if (threadIdx.x == 0) {
        float bsum = sdata[0] + sdata[1] + sdata[2] + sdata[3];
        atomicAdd(out, bsum * inv_b);
    }
}

extern "C" void kernel_launch(void* const* d_in, const int* in_sizes, int n_in,
                              void* d_out, int out_size, void* d_ws, size_t ws_size,
                              hipStream_t stream) {
    const float* logits  = (const float*)d_in[0];
    const int*   targets = (const int*)d_in[1];
    const float* cw      = (const float*)d_in[2];
    float* out = (float*)d_out;

    const int B = in_sizes[1];        // 8388608
    const int nquads = B / 4;         // B divisible by 4
    const float inv_b = 1.0f / (float)B;

    // d_out is re-poisoned to 0xAA before every timed launch
    hipMemsetAsync(out, 0, out_size * sizeof(float), stream);

    const int threads = 256;
    const int blocks  = 2048;         // 8 blocks/CU, 32 waves/CU; ~16 rows/thread
    trading_loss_kernel<<<blocks, threads, 0, stream>>>(
        logits, targets, cw, out, nquads, inv_b);
}

// Round 2
// 176.251 us; speedup vs baseline: 1.0226x; 1.0226x over previous
//
#include <hip/hip_runtime.h>

#define DIRECTIONAL_PENALTY 1.5f
#define CONFIDENCE_WEIGHT 0.1f

// Per-row loss contribution. 3 logits a,b,c; target t; class weights w0..w2.
__device__ __forceinline__ float row_loss(float a, float b, float c, int t,
                                          float w0, float w1, float w2) {
    // argmax, first-max tie semantics (strict >)
    int pred = 0;
    float m = a;
    if (b > m) { m = b; pred = 1; }
    if (c > m) { m = c; pred = 2; }

    float e0 = __expf(a - m);
    float e1 = __expf(b - m);
    float e2 = __expf(c - m);
    float s = e0 + e1 + e2;
    float inv_s = 1.0f / s;

    float et = (t == 0) ? e0 : ((t == 1) ? e1 : e2);
    float lt = (t == 0) ? a  : ((t == 1) ? b  : c);
    float p_t = et * inv_s;
    float ce = (m - lt) + __logf(s);   // -log_softmax[target]

    float w  = (t == 0) ? w0 : ((t == 1) ? w1 : w2);
    float omp = 1.0f - p_t;
    float contrib = w * omp * omp * ce;               // focal term

    // penalty matrix is Toeplitz in |pred-t|: 0->0, 1->0.5, 2->1.5
    int d = pred - t; d = (d < 0) ? -d : d;
    float pen = (d == 1) ? 0.5f : ((d == 2) ? 1.5f : 0.0f);
    contrib += DIRECTIONAL_PENALTY * pen;

    // confidence: (1-correct) * max_prob; max_prob = exp(m-m)/s = 1/s
    if (pred != t) contrib += CONFIDENCE_WEIGHT * inv_s;
    return contrib;
}

// Tile = 1024 rows = 3072 floats = 768 float4 = 12 KB LDS.
__global__ __launch_bounds__(256) void tsl_partial(
    const float* __restrict__ logits,    // [B,3]
    const int*   __restrict__ targets,   // [B]
    const float* __restrict__ cw,        // [3]
    float*       __restrict__ partial,   // [gridDim.x]
    int nTiles, int B)
{
    __shared__ __align__(16) float smem[3072];
    const float w0 = cw[0], w1 = cw[1], w2 = cw[2];
    const int tid = threadIdx.x;

    float acc = 0.0f;

    for (int tile = blockIdx.x; tile < nTiles; tile += gridDim.x) {
        // coalesced global -> LDS stage: 3 x dwordx4 per thread
        const float4* __restrict__ g4 = (const float4*)logits + (size_t)tile * 768;
        float4* s4 = (float4*)smem;
        s4[tid]       = g4[tid];
        s4[tid + 256] = g4[tid + 256];
        s4[tid + 512] = g4[tid + 512];
        __syncthreads();

        const int rowBase = tile * 1024;
        #pragma unroll
        for (int j = 0; j < 4; ++j) {
            const int lr = tid + 256 * j;                 // local row
            // LDS read: byte addr 12*lr -> bank 3*lr mod 32, 2 lanes/bank = conflict-free
            float a = smem[3 * lr + 0];
            float b = smem[3 * lr + 1];
            float c = smem[3 * lr + 2];
            int   t = targets[rowBase + lr];              // coalesced
            acc += row_loss(a, b, c, t, w0, w1, w2);
        }
        __syncthreads();   // before next tile overwrites smem
    }

    // remainder rows (none at B=8388608, kept for generality)
    for (int r = nTiles * 1024 + blockIdx.x * 256 + tid; r < B;
         r += gridDim.x * 256) {
        float a = logits[3 * r + 0];
        float b = logits[3 * r + 1];
        float c = logits[3 * r + 2];
        acc += row_loss(a, b, c, targets[r], w0, w1, w2);
    }

    // wave64 shuffle reduction
    #pragma unroll
    for (int off = 32; off > 0; off >>= 1)
        acc += __shfl_down(acc, off, 64);

    __shared__ float sdata[4];
    const int lane = tid & 63;
    const int wid  = tid >> 6;
    if (lane == 0) sdata[wid] = acc;
    __syncthreads();
    if (tid == 0)
        partial[blockIdx.x] = sdata[0] + sdata[1] + sdata[2] + sdata[3];
}

__global__ __launch_bounds__(256) void tsl_final(
    const float* __restrict__ partial, int n,
    float* __restrict__ out, float inv_b)
{
    float acc = 0.0f;
    for (int i = threadIdx.x; i < n; i += 256) acc += partial[i];

    #pragma unroll
    for (int off = 32; off > 0; off >>= 1)
        acc += __shfl_down(acc, off, 64);

    __shared__ float sdata[4];
    const int lane = threadIdx.x & 63;
    const int wid  = threadIdx.x >> 6;
    if (lane == 0) sdata[wid] = acc;
    __syncthreads();
    if (threadIdx.x == 0)
        out[0] = (sdata[0] + sdata[1] + sdata[2] + sdata[3]) * inv_b;
}

extern "C" void kernel_launch(void* const* d_in, const int* in_sizes, int n_in,
                              void* d_out, int out_size, void* d_ws, size_t ws_size,
                              hipStream_t stream) {
    const float* logits  = (const float*)d_in[0];
    const int*   targets = (const int*)d_in[1];
    const float* cw      = (const float*)d_in[2];
    float* out     = (float*)d_out;
    float* partial = (float*)d_ws;         // 2048 floats, fully overwritten

    const int B = in_sizes[1];             // 8388608
    const int nTiles = B / 1024;           // 8192
    const float inv_b = 1.0f / (float)B;

    const int blocks = 2048;               // 4 tiles/block, 8 blocks/CU
    tsl_partial<<<blocks, 256, 0, stream>>>(logits, targets, cw, partial, nTiles, B);
    tsl_final<<<1, 256, 0, stream>>>(partial, blocks, out, inv_b);
}